// Round 6
// baseline (2720.000 us; speedup 1.0000x reference)
//
#include <hip/hip_runtime.h>
#include <cstdint>
#include <cstddef>

#define B_ROWS 16384
#define DIM 1024
#define ORDH 512
#define NEXP 7

__global__ void init_kernel(int* gcnt) {
  if (threadIdx.x < NEXP) gcnt[threadIdx.x] = 0;
}

// ---------------------------------------------------------------------------
// Plain fp32 vector GEMM: out = relu(A[M,K] * B[K,N] + bias). 64x64 tile,
// 256 threads, 4x4 micro-tile. B in natural [K][N] layout.
// ---------------------------------------------------------------------------
__global__ __launch_bounds__(256, 2) void vgemm_kernel(
    const float* __restrict__ A, const float* __restrict__ B, int K, int N,
    const float* __restrict__ bias, float* __restrict__ out, int ldo) {
  __shared__ float As[16][68];
  __shared__ float Bs[16][68];
  const int tid = threadIdx.x;
  const int m0 = blockIdx.y * 64;
  const int n0 = blockIdx.x * 64;
  const int lm = tid >> 2, lk4 = (tid & 3) * 4;
  const int lk = tid >> 4, ln4 = (tid & 15) * 4;
  const int tr = (tid >> 4) * 4, tc = (tid & 15) * 4;

  float acc[4][4] = {};
  for (int kt = 0; kt < K; kt += 16) {
    const float4 a4 = *(const float4*)&A[(size_t)(m0 + lm) * K + kt + lk4];
    const float4 b4 = *(const float4*)&B[(size_t)(kt + lk) * N + n0 + ln4];
    __syncthreads();
    As[lk4 + 0][lm] = a4.x;
    As[lk4 + 1][lm] = a4.y;
    As[lk4 + 2][lm] = a4.z;
    As[lk4 + 3][lm] = a4.w;
    *(float4*)&Bs[lk][ln4] = b4;
    __syncthreads();
#pragma unroll
    for (int k = 0; k < 16; ++k) {
      const float4 av = *(const float4*)&As[k][tr];
      const float4 bv = *(const float4*)&Bs[k][tc];
      const float am[4] = {av.x, av.y, av.z, av.w};
      const float bn[4] = {bv.x, bv.y, bv.z, bv.w};
#pragma unroll
      for (int i = 0; i < 4; ++i)
#pragma unroll
        for (int j = 0; j < 4; ++j) acc[i][j] += am[i] * bn[j];
    }
  }
#pragma unroll
  for (int i = 0; i < 4; ++i) {
    const int row = m0 + tr + i;
#pragma unroll
    for (int j = 0; j < 4; ++j) {
      const int col = n0 + tc + j;
      float v = acc[i][j] + bias[col];
      v = v > 0.f ? v : 0.f;
      out[(size_t)row * ldo + col] = v;
    }
  }
}

// expert-segmented variant: A rows [off[e]+t0, off[e]+cnt[e]) of permuted buffer
__global__ __launch_bounds__(256, 2) void vgemm_expert_kernel(
    const float* __restrict__ Abuf, const float* __restrict__ Wall,
    const float* __restrict__ biasAll, const int* __restrict__ off,
    const int* __restrict__ cnt, float* __restrict__ out) {
  __shared__ float As[16][68];
  __shared__ float Bs[16][68];
  const int e = blockIdx.z;
  const int myCnt = cnt[e];
  const int t0 = blockIdx.y * 64;
  if (t0 >= myCnt) return;  // uniform per block
  const int base = off[e];
  const int m0 = base + t0;
  const int mEnd = base + myCnt;
  const float* B = Wall + (size_t)e * DIM * DIM;
  const float* bias = biasAll + e * DIM;

  const int tid = threadIdx.x;
  const int n0 = blockIdx.x * 64;
  const int lm = tid >> 2, lk4 = (tid & 3) * 4;
  const int lk = tid >> 4, ln4 = (tid & 15) * 4;
  const int tr = (tid >> 4) * 4, tc = (tid & 15) * 4;

  float acc[4][4] = {};
  for (int kt = 0; kt < DIM; kt += 16) {
    int ar = m0 + lm;
    if (ar > B_ROWS - 1) ar = B_ROWS - 1;  // clamp; garbage masked at store
    const float4 a4 = *(const float4*)&Abuf[(size_t)ar * DIM + kt + lk4];
    const float4 b4 = *(const float4*)&B[(size_t)(kt + lk) * DIM + n0 + ln4];
    __syncthreads();
    As[lk4 + 0][lm] = a4.x;
    As[lk4 + 1][lm] = a4.y;
    As[lk4 + 2][lm] = a4.z;
    As[lk4 + 3][lm] = a4.w;
    *(float4*)&Bs[lk][ln4] = b4;
    __syncthreads();
#pragma unroll
    for (int k = 0; k < 16; ++k) {
      const float4 av = *(const float4*)&As[k][tr];
      const float4 bv = *(const float4*)&Bs[k][tc];
      const float am[4] = {av.x, av.y, av.z, av.w};
      const float bn[4] = {bv.x, bv.y, bv.z, bv.w};
#pragma unroll
      for (int i = 0; i < 4; ++i)
#pragma unroll
        for (int j = 0; j < 4; ++j) acc[i][j] += am[i] * bn[j];
    }
  }
#pragma unroll
  for (int i = 0; i < 4; ++i) {
    const int row = m0 + tr + i;
    if (row < mEnd) {
#pragma unroll
      for (int j = 0; j < 4; ++j) {
        const int col = n0 + tc + j;
        float v = acc[i][j] + bias[col];
        v = v > 0.f ? v : 0.f;
        out[(size_t)row * DIM + col] = v;
      }
    }
  }
}

// ---------------------------------------------------------------------------
// head kernels: one wave per row, shuffle reduction. OUTPUT IS float32.
// out layout per row (24): [logits 0..6 | ord 7..12 | reg 13 | probs 14..20 |
//                           depth 21..23]
// ---------------------------------------------------------------------------
__global__ __launch_bounds__(256) void head_res_kernel(
    const float* __restrict__ Y3, const float* __restrict__ Wr2,
    const float* __restrict__ br2, float* __restrict__ resv) {
  const int lane = threadIdx.x & 63;
  const int r = blockIdx.x * 4 + (threadIdx.x >> 6);
  float s = 0.f;
  for (int it = 0; it < 16; ++it) {
    const int k = it * 64 + lane;
    s += Y3[(size_t)r * DIM + k] * Wr2[k];
  }
  for (int o = 32; o > 0; o >>= 1) s += __shfl_down(s, o);
  if (lane == 0) resv[r] = 0.35f * tanhf(s + br2[0]);
}

__global__ __launch_bounds__(256) void head_ord_kernel(
    const float* __restrict__ Y2, const float* __restrict__ Wo2,
    const float* __restrict__ bo2, float* __restrict__ out) {
  const int lane = threadIdx.x & 63;
  const int r = blockIdx.x * 4 + (threadIdx.x >> 6);
  float s[6] = {0, 0, 0, 0, 0, 0};
  for (int it = 0; it < 8; ++it) {
    const int k = it * 64 + lane;
    const float v = Y2[(size_t)r * ORDH + k];
    const float* wr = Wo2 + k * 6;
#pragma unroll
    for (int n = 0; n < 6; ++n) s[n] += v * wr[n];
  }
#pragma unroll
  for (int n = 0; n < 6; ++n) {
    float xv = s[n];
    for (int o = 32; o > 0; o >>= 1) xv += __shfl_down(xv, o);
    s[n] = xv;
  }
  if (lane == 0) {
#pragma unroll
    for (int n = 0; n < 6; ++n) out[(size_t)r * 24 + 7 + n] = s[n] + bo2[n];
  }
}

__global__ __launch_bounds__(256) void head_cls_kernel(
    const float* __restrict__ Y1, const float* __restrict__ Wc2,
    const float* __restrict__ bc2, const float* __restrict__ resv,
    float* __restrict__ out, int* __restrict__ size_idx, int* __restrict__ gcnt) {
  __shared__ int lcnt[NEXP];
  const int tid = threadIdx.x;
  if (tid < NEXP) lcnt[tid] = 0;
  __syncthreads();
  const int lane = tid & 63;
  const int r = blockIdx.x * 4 + (tid >> 6);
  float s[7] = {0, 0, 0, 0, 0, 0, 0};
  for (int it = 0; it < 16; ++it) {
    const int k = it * 64 + lane;
    const float v = Y1[(size_t)r * DIM + k];
    const float* wr = Wc2 + k * 7;
#pragma unroll
    for (int n = 0; n < 7; ++n) s[n] += v * wr[n];
  }
#pragma unroll
  for (int n = 0; n < 7; ++n) {
    float xv = s[n];
    for (int o = 32; o > 0; o >>= 1) xv += __shfl_down(xv, o);
    s[n] = xv;
  }
  if (lane == 0) {
    float lg[7], p[7];
    float m = -1e30f;
    int ai = 0;
#pragma unroll
    for (int n = 0; n < 7; ++n) {
      lg[n] = s[n] + bc2[n];
      if (lg[n] > m) { m = lg[n]; ai = n; }  // first max == np.argmax
    }
    float es = 0.f;
#pragma unroll
    for (int n = 0; n < 7; ++n) { p[n] = expf(lg[n] - m); es += p[n]; }
    const float inv = 1.f / es;
    float expect = 0.f;
#pragma unroll
    for (int n = 0; n < 7; ++n) { p[n] *= inv; expect += p[n] * (n * (1.f / 6.f)); }
    float reg = expect + resv[r];
    reg = fminf(fmaxf(reg, 0.f), 1.f);
    float* orow = out + (size_t)r * 24;
#pragma unroll
    for (int n = 0; n < 7; ++n) orow[n] = lg[n];
    orow[13] = reg;
#pragma unroll
    for (int n = 0; n < 7; ++n) orow[14 + n] = p[n];
    size_idx[r] = ai;
    atomicAdd(&lcnt[ai], 1);
  }
  __syncthreads();
  if (tid < NEXP && lcnt[tid] > 0) atomicAdd(&gcnt[tid], lcnt[tid]);
}

__global__ void scan_kernel(const int* __restrict__ gcnt, int* __restrict__ off,
                            int* __restrict__ cursor) {
  if (threadIdx.x == 0) {
    int a = 0;
    for (int e = 0; e < NEXP; ++e) { off[e] = a; cursor[e] = a; a += gcnt[e]; }
    off[NEXP] = a;
  }
}

__global__ __launch_bounds__(256) void scatter_kernel(
    const int* __restrict__ size_idx, int* __restrict__ cursor,
    int* __restrict__ perm) {
  __shared__ int lcnt[NEXP];
  __shared__ int lbase[NEXP];
  const int tid = threadIdx.x;
  if (tid < NEXP) lcnt[tid] = 0;
  __syncthreads();
  const int r = blockIdx.x * 256 + tid;
  const int e = size_idx[r];
  const int lp = atomicAdd(&lcnt[e], 1);
  __syncthreads();
  if (tid < NEXP && lcnt[tid] > 0) lbase[tid] = atomicAdd(&cursor[tid], lcnt[tid]);
  __syncthreads();
  perm[lbase[e] + lp] = r;
}

__global__ __launch_bounds__(256) void permute_kernel(
    const float* __restrict__ DF, const int* __restrict__ perm,
    float* __restrict__ DFp) {
  const int i = blockIdx.x;
  const int src = perm[i];
  const float4* s = (const float4*)(DF + (size_t)src * DIM);
  float4* d = (float4*)(DFp + (size_t)i * DIM);
  d[threadIdx.x] = s[threadIdx.x];
}

__global__ __launch_bounds__(256) void head_dl_kernel(
    const float* __restrict__ H2p, const float* __restrict__ We3,
    const float* __restrict__ be3, const int* __restrict__ off,
    const int* __restrict__ perm, float* __restrict__ out) {
  const int lane = threadIdx.x & 63;
  const int i = blockIdx.x * 4 + (threadIdx.x >> 6);
  int e = 0;
#pragma unroll
  for (int t = 1; t < NEXP; ++t)
    if (i >= off[t]) e = t;
  const float* W = We3 + (size_t)e * DIM * 3;
  float s0 = 0.f, s1 = 0.f, s2 = 0.f;
  for (int it = 0; it < 16; ++it) {
    const int k = it * 64 + lane;
    const float v = H2p[(size_t)i * DIM + k];
    s0 += v * W[k * 3 + 0];
    s1 += v * W[k * 3 + 1];
    s2 += v * W[k * 3 + 2];
  }
  for (int o = 32; o > 0; o >>= 1) {
    s0 += __shfl_down(s0, o);
    s1 += __shfl_down(s1, o);
    s2 += __shfl_down(s2, o);
  }
  if (lane == 0) {
    const int r = perm[i];
    float* orow = out + (size_t)r * 24;
    orow[21] = s0 + be3[e * 3 + 0];
    orow[22] = s1 + be3[e * 3 + 1];
    orow[23] = s2 + be3[e * 3 + 2];
  }
}

// ---------------------------------------------------------------------------
extern "C" void kernel_launch(void* const* d_in, const int* in_sizes, int n_in,
                              void* d_out, int out_size, void* d_ws, size_t ws_size,
                              hipStream_t stream) {
  (void)in_sizes; (void)n_in; (void)out_size; (void)ws_size;
  const float* x   = (const float*)d_in[0];
  const float* Wc1 = (const float*)d_in[1];
  const float* bc1 = (const float*)d_in[2];
  const float* Wc2 = (const float*)d_in[3];
  const float* bc2 = (const float*)d_in[4];
  const float* Wo1 = (const float*)d_in[5];
  const float* bo1 = (const float*)d_in[6];
  const float* Wo2 = (const float*)d_in[7];
  const float* bo2 = (const float*)d_in[8];
  const float* Wr1 = (const float*)d_in[9];
  const float* br1 = (const float*)d_in[10];
  const float* Wr2 = (const float*)d_in[11];
  const float* br2 = (const float*)d_in[12];
  const float* Wa  = (const float*)d_in[13];
  const float* ba  = (const float*)d_in[14];
  const float* We1 = (const float*)d_in[15];
  const float* be1 = (const float*)d_in[16];
  const float* We2 = (const float*)d_in[17];
  const float* be2 = (const float*)d_in[18];
  const float* We3 = (const float*)d_in[19];
  const float* be3 = (const float*)d_in[20];
  float* out = (float*)d_out;  // reference output dtype is float32

  char* p = (char*)d_ws;
  auto carve = [&](size_t bytes) {
    char* r = p;
    p += (bytes + 255) & ~(size_t)255;
    return r;
  };
  float* Y1 = (float*)carve((size_t)B_ROWS * DIM * 4);   // cls hidden
  float* Y2 = (float*)carve((size_t)B_ROWS * ORDH * 4);  // ord hidden
  float* Y3 = (float*)carve((size_t)B_ROWS * DIM * 4);   // res hidden
  float* DF = (float*)carve((size_t)B_ROWS * DIM * 4);   // depth_feat
  float* resv = (float*)carve((size_t)B_ROWS * 4);
  int* size_idx = (int*)carve((size_t)B_ROWS * 4);
  int* perm   = (int*)carve((size_t)B_ROWS * 4);
  int* gcnt   = (int*)carve(256);
  int* off    = (int*)carve(256);
  int* cursor = (int*)carve(256);
  // aliases over dead intervals (stream-ordered):
  float* DFp = Y3;  // Y3 dead after head_res
  float* H1p = Y1;  // Y1 dead after head_cls
  float* H2p = DF;  // DF dead after permute

  dim3 blk(256);
  init_kernel<<<dim3(1), dim3(64), 0, stream>>>(gcnt);

  // hidden layers: relu(x @ W + b), W in natural [K][N] layout
  vgemm_kernel<<<dim3(DIM / 64, B_ROWS / 64), blk, 0, stream>>>(
      x, Wc1, DIM, DIM, bc1, Y1, DIM);
  vgemm_kernel<<<dim3(ORDH / 64, B_ROWS / 64), blk, 0, stream>>>(
      x, Wo1, DIM, ORDH, bo1, Y2, ORDH);
  vgemm_kernel<<<dim3(DIM / 64, B_ROWS / 64), blk, 0, stream>>>(
      x, Wr1, DIM, DIM, br1, Y3, DIM);
  vgemm_kernel<<<dim3(DIM / 64, B_ROWS / 64), blk, 0, stream>>>(
      x, Wa, DIM, DIM, ba, DF, DIM);

  head_res_kernel<<<dim3(B_ROWS / 4), blk, 0, stream>>>(Y3, Wr2, br2, resv);
  head_ord_kernel<<<dim3(B_ROWS / 4), blk, 0, stream>>>(Y2, Wo2, bo2, out);
  head_cls_kernel<<<dim3(B_ROWS / 4), blk, 0, stream>>>(Y1, Wc2, bc2, resv, out,
                                                        size_idx, gcnt);
  scan_kernel<<<dim3(1), dim3(64), 0, stream>>>(gcnt, off, cursor);
  scatter_kernel<<<dim3(B_ROWS / 256), blk, 0, stream>>>(size_idx, cursor, perm);
  permute_kernel<<<dim3(B_ROWS), blk, 0, stream>>>(DF, perm, DFp);

  vgemm_expert_kernel<<<dim3(DIM / 64, B_ROWS / 64, NEXP), blk, 0, stream>>>(
      DFp, We1, be1, off, gcnt, H1p);
  vgemm_expert_kernel<<<dim3(DIM / 64, B_ROWS / 64, NEXP), blk, 0, stream>>>(
      H1p, We2, be2, off, gcnt, H2p);
  head_dl_kernel<<<dim3(B_ROWS / 4), blk, 0, stream>>>(H2p, We3, be3, off, perm, out);
}

// Round 7
// 1759.888 us; speedup vs baseline: 1.5456x; 1.5456x over previous
//
#include <hip/hip_runtime.h>
#include <cstdint>
#include <cstddef>

typedef unsigned short u16;
typedef u16 u16x8 __attribute__((ext_vector_type(8)));
typedef __bf16 bf16x8 __attribute__((ext_vector_type(8)));
typedef float f32x4 __attribute__((ext_vector_type(4)));

#define B_ROWS 16384
#define DIM 1024
#define ORDH 512
#define NEXP 7
#define LDST 72  // LDS row stride in u16 (64 data + 8 pad)

__device__ __forceinline__ u16 f2bf(float f) {
  unsigned u = __builtin_bit_cast(unsigned, f);
  u += 0x7FFFu + ((u >> 16) & 1u);  // RNE
  return (u16)(u >> 16);
}
__device__ __forceinline__ float bf2f(u16 h) {
  return __builtin_bit_cast(float, ((unsigned)h) << 16);
}

__global__ void init_kernel(int* gcnt) {
  if (threadIdx.x < NEXP) gcnt[threadIdx.x] = 0;
}

// x fp32 -> bf16
__global__ __launch_bounds__(256) void convert_x_kernel(
    const float4* __restrict__ x, ushort4* __restrict__ xh) {
  const int i = blockIdx.x * 256 + threadIdx.x;
  float4 v = x[i];
  ushort4 h;
  h.x = f2bf(v.x); h.y = f2bf(v.y); h.z = f2bf(v.z); h.w = f2bf(v.w);
  xh[i] = h;
}

// W [K][N] f32 -> WT [N][K] bf16. grid z = expert batch.
__global__ __launch_bounds__(256) void transpose_kernel(
    const float* __restrict__ W, u16* __restrict__ WT, int K, int N) {
  __shared__ float tile[32][33];
  const int bk = blockIdx.y * 32, bn = blockIdx.x * 32;
  const int tx = threadIdx.x & 31, ty = threadIdx.x >> 5;  // 32 x 8
  const size_t zoff = (size_t)blockIdx.z * K * N;
#pragma unroll
  for (int r = 0; r < 32; r += 8)
    tile[ty + r][tx] = W[zoff + (size_t)(bk + ty + r) * N + (bn + tx)];
  __syncthreads();
#pragma unroll
  for (int r = 0; r < 32; r += 8)
    WT[zoff + (size_t)(bn + ty + r) * K + (bk + tx)] = f2bf(tile[tx][ty + r]);
}

// ---------------------------------------------------------------------------
// bf16 MFMA GEMM: out = relu(A[M,K] * B^T + bias); B = WT [N,K] bf16.
// 128x128x64 tile, 4 waves (2x2), 4x4 mfma 16x16x32 each. Register staging.
// (machinery validated: rounds 1/2 computed values identical to fp32 path)
// ---------------------------------------------------------------------------
__global__ __launch_bounds__(256, 2) void mgemm_bt_kernel(
    const u16* __restrict__ A, const u16* __restrict__ Bm, int K,
    const float* __restrict__ bias, u16* __restrict__ outH, int ldo) {
  __shared__ __attribute__((aligned(16))) u16 As[128 * LDST];
  __shared__ __attribute__((aligned(16))) u16 Bs[128 * LDST];
  const int tid = threadIdx.x;
  const int lane = tid & 63;
  const int w = tid >> 6;
  const int wm = w >> 1, wn = w & 1;
  const int m0 = blockIdx.y * 128;
  const int n0 = blockIdx.x * 128;
  const int sRow = tid >> 3;
  const int sSlot = tid & 7;

  f32x4 acc[4][4] = {};
  for (int kt = 0; kt < K; kt += 64) {
    int4 av[4], bv[4];
#pragma unroll
    for (int r = 0; r < 4; ++r) {
      const int row = r * 32 + sRow;
      av[r] = *(const int4*)(A + (size_t)(m0 + row) * K + kt + sSlot * 8);
      bv[r] = *(const int4*)(Bm + (size_t)(n0 + row) * K + kt + sSlot * 8);
    }
    __syncthreads();
#pragma unroll
    for (int r = 0; r < 4; ++r) {
      const int row = r * 32 + sRow;
      *(int4*)&As[row * LDST + sSlot * 8] = av[r];
      *(int4*)&Bs[row * LDST + sSlot * 8] = bv[r];
    }
    __syncthreads();
#pragma unroll
    for (int s = 0; s < 2; ++s) {
      bf16x8 af[4], bfr[4];
      const int cA = s * 4 + (lane >> 4);
#pragma unroll
      for (int t = 0; t < 4; ++t) {
        const int rowA = wm * 64 + t * 16 + (lane & 15);
        af[t] = __builtin_bit_cast(bf16x8, *(const u16x8*)&As[rowA * LDST + cA * 8]);
        const int rowB = wn * 64 + t * 16 + (lane & 15);
        bfr[t] = __builtin_bit_cast(bf16x8, *(const u16x8*)&Bs[rowB * LDST + cA * 8]);
      }
#pragma unroll
      for (int mt = 0; mt < 4; ++mt)
#pragma unroll
        for (int nt = 0; nt < 4; ++nt)
          acc[mt][nt] = __builtin_amdgcn_mfma_f32_16x16x32_bf16(
              af[mt], bfr[nt], acc[mt][nt], 0, 0, 0);
    }
  }
  const int q = lane >> 4, cl = lane & 15;
#pragma unroll
  for (int nt = 0; nt < 4; ++nt) {
    const int col = n0 + wn * 64 + nt * 16 + cl;
    const float bv = bias[col];
#pragma unroll
    for (int mt = 0; mt < 4; ++mt) {
#pragma unroll
      for (int i = 0; i < 4; ++i) {
        const int row = m0 + wm * 64 + mt * 16 + q * 4 + i;
        float v = acc[mt][nt][i] + bv;
        v = v > 0.f ? v : 0.f;
        outH[(size_t)row * ldo + col] = f2bf(v);
      }
    }
  }
}

// expert-segmented MFMA variant: rows [off[e]+t0, off[e]+cnt[e])
__global__ __launch_bounds__(256, 2) void mgemm_expert_kernel(
    const u16* __restrict__ Abuf, const u16* __restrict__ Wall,
    const float* __restrict__ biasAll, const int* __restrict__ off,
    const int* __restrict__ cnt, u16* __restrict__ outH) {
  __shared__ __attribute__((aligned(16))) u16 As[128 * LDST];
  __shared__ __attribute__((aligned(16))) u16 Bs[128 * LDST];
  const int e = blockIdx.z;
  const int myCnt = cnt[e];
  const int t0 = blockIdx.y * 128;
  if (t0 >= myCnt) return;  // uniform per block
  const int base = off[e];
  const int m0 = base + t0;
  const int mEnd = base + myCnt;
  const u16* Bp = Wall + (size_t)e * DIM * DIM;
  const float* bias = biasAll + (size_t)e * DIM;

  const int tid = threadIdx.x;
  const int lane = tid & 63;
  const int w = tid >> 6;
  const int wm = w >> 1, wn = w & 1;
  const int n0 = blockIdx.x * 128;
  const int sRow = tid >> 3;
  const int sSlot = tid & 7;

  f32x4 acc[4][4] = {};
  for (int kt = 0; kt < DIM; kt += 64) {
    int4 av[4], bv[4];
#pragma unroll
    for (int r = 0; r < 4; ++r) {
      int ar = m0 + r * 32 + sRow;
      if (ar > B_ROWS - 1) ar = B_ROWS - 1;  // clamp; masked at store
      av[r] = *(const int4*)(Abuf + (size_t)ar * DIM + kt + sSlot * 8);
      bv[r] = *(const int4*)(Bp + (size_t)(n0 + r * 32 + sRow) * DIM + kt + sSlot * 8);
    }
    __syncthreads();
#pragma unroll
    for (int r = 0; r < 4; ++r) {
      const int row = r * 32 + sRow;
      *(int4*)&As[row * LDST + sSlot * 8] = av[r];
      *(int4*)&Bs[row * LDST + sSlot * 8] = bv[r];
    }
    __syncthreads();
#pragma unroll
    for (int s = 0; s < 2; ++s) {
      bf16x8 af[4], bfr[4];
      const int cA = s * 4 + (lane >> 4);
#pragma unroll
      for (int t = 0; t < 4; ++t) {
        const int rowA = wm * 64 + t * 16 + (lane & 15);
        af[t] = __builtin_bit_cast(bf16x8, *(const u16x8*)&As[rowA * LDST + cA * 8]);
        const int rowB = wn * 64 + t * 16 + (lane & 15);
        bfr[t] = __builtin_bit_cast(bf16x8, *(const u16x8*)&Bs[rowB * LDST + cA * 8]);
      }
#pragma unroll
      for (int mt = 0; mt < 4; ++mt)
#pragma unroll
        for (int nt = 0; nt < 4; ++nt)
          acc[mt][nt] = __builtin_amdgcn_mfma_f32_16x16x32_bf16(
              af[mt], bfr[nt], acc[mt][nt], 0, 0, 0);
    }
  }
  const int q = lane >> 4, cl = lane & 15;
#pragma unroll
  for (int nt = 0; nt < 4; ++nt) {
    const int col = n0 + wn * 64 + nt * 16 + cl;
    const float bv = bias[col];
#pragma unroll
    for (int mt = 0; mt < 4; ++mt) {
#pragma unroll
      for (int i = 0; i < 4; ++i) {
        const int row = m0 + wm * 64 + mt * 16 + q * 4 + i;
        if (row < mEnd) {
          float v = acc[mt][nt][i] + bv;
          v = v > 0.f ? v : 0.f;
          outH[(size_t)row * DIM + col] = f2bf(v);
        }
      }
    }
  }
}

// ---------------------------------------------------------------------------
// fp32 vector GEMM (kept ONLY for the cls hidden layer -> bit-identical route)
// ---------------------------------------------------------------------------
__global__ __launch_bounds__(256, 2) void vgemm_kernel(
    const float* __restrict__ A, const float* __restrict__ B, int K, int N,
    const float* __restrict__ bias, float* __restrict__ out, int ldo) {
  __shared__ float As[16][68];
  __shared__ float Bs[16][68];
  const int tid = threadIdx.x;
  const int m0 = blockIdx.y * 64;
  const int n0 = blockIdx.x * 64;
  const int lm = tid >> 2, lk4 = (tid & 3) * 4;
  const int lk = tid >> 4, ln4 = (tid & 15) * 4;
  const int tr = (tid >> 4) * 4, tc = (tid & 15) * 4;

  float acc[4][4] = {};
  for (int kt = 0; kt < K; kt += 16) {
    const float4 a4 = *(const float4*)&A[(size_t)(m0 + lm) * K + kt + lk4];
    const float4 b4 = *(const float4*)&B[(size_t)(kt + lk) * N + n0 + ln4];
    __syncthreads();
    As[lk4 + 0][lm] = a4.x;
    As[lk4 + 1][lm] = a4.y;
    As[lk4 + 2][lm] = a4.z;
    As[lk4 + 3][lm] = a4.w;
    *(float4*)&Bs[lk][ln4] = b4;
    __syncthreads();
#pragma unroll
    for (int k = 0; k < 16; ++k) {
      const float4 av = *(const float4*)&As[k][tr];
      const float4 bv = *(const float4*)&Bs[k][tc];
      const float am[4] = {av.x, av.y, av.z, av.w};
      const float bn[4] = {bv.x, bv.y, bv.z, bv.w};
#pragma unroll
      for (int i = 0; i < 4; ++i)
#pragma unroll
        for (int j = 0; j < 4; ++j) acc[i][j] += am[i] * bn[j];
    }
  }
#pragma unroll
  for (int i = 0; i < 4; ++i) {
    const int row = m0 + tr + i;
#pragma unroll
    for (int j = 0; j < 4; ++j) {
      const int col = n0 + tc + j;
      float v = acc[i][j] + bias[col];
      v = v > 0.f ? v : 0.f;
      out[(size_t)row * ldo + col] = v;
    }
  }
}

// ---------------------------------------------------------------------------
// heads: one wave per row. OUTPUT fp32.
// ---------------------------------------------------------------------------
__global__ __launch_bounds__(256) void head_res_kernel(
    const u16* __restrict__ Y3, const float* __restrict__ Wr2,
    const float* __restrict__ br2, float* __restrict__ resv) {
  const int lane = threadIdx.x & 63;
  const int r = blockIdx.x * 4 + (threadIdx.x >> 6);
  float s = 0.f;
  for (int it = 0; it < 16; ++it) {
    const int k = it * 64 + lane;
    s += bf2f(Y3[(size_t)r * DIM + k]) * Wr2[k];
  }
  for (int o = 32; o > 0; o >>= 1) s += __shfl_down(s, o);
  if (lane == 0) resv[r] = 0.35f * tanhf(s + br2[0]);
}

__global__ __launch_bounds__(256) void head_ord_kernel(
    const u16* __restrict__ Y2, const float* __restrict__ Wo2,
    const float* __restrict__ bo2, float* __restrict__ out) {
  const int lane = threadIdx.x & 63;
  const int r = blockIdx.x * 4 + (threadIdx.x >> 6);
  float s[6] = {0, 0, 0, 0, 0, 0};
  for (int it = 0; it < 8; ++it) {
    const int k = it * 64 + lane;
    const float v = bf2f(Y2[(size_t)r * ORDH + k]);
    const float* wr = Wo2 + k * 6;
#pragma unroll
    for (int n = 0; n < 6; ++n) s[n] += v * wr[n];
  }
#pragma unroll
  for (int n = 0; n < 6; ++n) {
    float xv = s[n];
    for (int o = 32; o > 0; o >>= 1) xv += __shfl_down(xv, o);
    s[n] = xv;
  }
  if (lane == 0) {
#pragma unroll
    for (int n = 0; n < 6; ++n) out[(size_t)r * 24 + 7 + n] = s[n] + bo2[n];
  }
}

__global__ __launch_bounds__(256) void head_cls_kernel(
    const float* __restrict__ Y1, const float* __restrict__ Wc2,
    const float* __restrict__ bc2, const float* __restrict__ resv,
    float* __restrict__ out, int* __restrict__ size_idx, int* __restrict__ gcnt) {
  __shared__ int lcnt[NEXP];
  const int tid = threadIdx.x;
  if (tid < NEXP) lcnt[tid] = 0;
  __syncthreads();
  const int lane = tid & 63;
  const int r = blockIdx.x * 4 + (tid >> 6);
  float s[7] = {0, 0, 0, 0, 0, 0, 0};
  for (int it = 0; it < 16; ++it) {
    const int k = it * 64 + lane;
    const float v = Y1[(size_t)r * DIM + k];
    const float* wr = Wc2 + k * 7;
#pragma unroll
    for (int n = 0; n < 7; ++n) s[n] += v * wr[n];
  }
#pragma unroll
  for (int n = 0; n < 7; ++n) {
    float xv = s[n];
    for (int o = 32; o > 0; o >>= 1) xv += __shfl_down(xv, o);
    s[n] = xv;
  }
  if (lane == 0) {
    float lg[7], p[7];
    float m = -1e30f;
    int ai = 0;
#pragma unroll
    for (int n = 0; n < 7; ++n) {
      lg[n] = s[n] + bc2[n];
      if (lg[n] > m) { m = lg[n]; ai = n; }  // first max == np.argmax
    }
    float es = 0.f;
#pragma unroll
    for (int n = 0; n < 7; ++n) { p[n] = expf(lg[n] - m); es += p[n]; }
    const float inv = 1.f / es;
    float expect = 0.f;
#pragma unroll
    for (int n = 0; n < 7; ++n) { p[n] *= inv; expect += p[n] * (n * (1.f / 6.f)); }
    float reg = expect + resv[r];
    reg = fminf(fmaxf(reg, 0.f), 1.f);
    float* orow = out + (size_t)r * 24;
#pragma unroll
    for (int n = 0; n < 7; ++n) orow[n] = lg[n];
    orow[13] = reg;
#pragma unroll
    for (int n = 0; n < 7; ++n) orow[14 + n] = p[n];
    size_idx[r] = ai;
    atomicAdd(&lcnt[ai], 1);
  }
  __syncthreads();
  if (tid < NEXP && lcnt[tid] > 0) atomicAdd(&gcnt[tid], lcnt[tid]);
}

__global__ void scan_kernel(const int* __restrict__ gcnt, int* __restrict__ off,
                            int* __restrict__ cursor) {
  if (threadIdx.x == 0) {
    int a = 0;
    for (int e = 0; e < NEXP; ++e) { off[e] = a; cursor[e] = a; a += gcnt[e]; }
    off[NEXP] = a;
  }
}

__global__ __launch_bounds__(256) void scatter_kernel(
    const int* __restrict__ size_idx, int* __restrict__ cursor,
    int* __restrict__ perm) {
  __shared__ int lcnt[NEXP];
  __shared__ int lbase[NEXP];
  const int tid = threadIdx.x;
  if (tid < NEXP) lcnt[tid] = 0;
  __syncthreads();
  const int r = blockIdx.x * 256 + tid;
  const int e = size_idx[r];
  const int lp = atomicAdd(&lcnt[e], 1);
  __syncthreads();
  if (tid < NEXP && lcnt[tid] > 0) lbase[tid] = atomicAdd(&cursor[tid], lcnt[tid]);
  __syncthreads();
  perm[lbase[e] + lp] = r;
}

__global__ __launch_bounds__(256) void permute_kernel(
    const u16* __restrict__ DF, const int* __restrict__ perm,
    u16* __restrict__ DFp) {
  const int i = blockIdx.x;
  const int src = perm[i];
  const uint2* s = (const uint2*)(DF + (size_t)src * DIM);
  uint2* d = (uint2*)(DFp + (size_t)i * DIM);
  d[threadIdx.x] = s[threadIdx.x];
}

__global__ __launch_bounds__(256) void head_dl_kernel(
    const u16* __restrict__ H2p, const float* __restrict__ We3,
    const float* __restrict__ be3, const int* __restrict__ off,
    const int* __restrict__ perm, float* __restrict__ out) {
  const int lane = threadIdx.x & 63;
  const int i = blockIdx.x * 4 + (threadIdx.x >> 6);
  int e = 0;
#pragma unroll
  for (int t = 1; t < NEXP; ++t)
    if (i >= off[t]) e = t;
  const float* W = We3 + (size_t)e * DIM * 3;
  float s0 = 0.f, s1 = 0.f, s2 = 0.f;
  for (int it = 0; it < 16; ++it) {
    const int k = it * 64 + lane;
    const float v = bf2f(H2p[(size_t)i * DIM + k]);
    s0 += v * W[k * 3 + 0];
    s1 += v * W[k * 3 + 1];
    s2 += v * W[k * 3 + 2];
  }
  for (int o = 32; o > 0; o >>= 1) {
    s0 += __shfl_down(s0, o);
    s1 += __shfl_down(s1, o);
    s2 += __shfl_down(s2, o);
  }
  if (lane == 0) {
    const int r = perm[i];
    float* orow = out + (size_t)r * 24;
    orow[21] = s0 + be3[e * 3 + 0];
    orow[22] = s1 + be3[e * 3 + 1];
    orow[23] = s2 + be3[e * 3 + 2];
  }
}

// ---------------------------------------------------------------------------
extern "C" void kernel_launch(void* const* d_in, const int* in_sizes, int n_in,
                              void* d_out, int out_size, void* d_ws, size_t ws_size,
                              hipStream_t stream) {
  (void)in_sizes; (void)n_in; (void)out_size; (void)ws_size;
  const float* x   = (const float*)d_in[0];
  const float* Wc1 = (const float*)d_in[1];
  const float* bc1 = (const float*)d_in[2];
  const float* Wc2 = (const float*)d_in[3];
  const float* bc2 = (const float*)d_in[4];
  const float* Wo1 = (const float*)d_in[5];
  const float* bo1 = (const float*)d_in[6];
  const float* Wo2 = (const float*)d_in[7];
  const float* bo2 = (const float*)d_in[8];
  const float* Wr1 = (const float*)d_in[9];
  const float* br1 = (const float*)d_in[10];
  const float* Wr2 = (const float*)d_in[11];
  const float* br2 = (const float*)d_in[12];
  const float* Wa  = (const float*)d_in[13];
  const float* ba  = (const float*)d_in[14];
  const float* We1 = (const float*)d_in[15];
  const float* be1 = (const float*)d_in[16];
  const float* We2 = (const float*)d_in[17];
  const float* be2 = (const float*)d_in[18];
  const float* We3 = (const float*)d_in[19];
  const float* be3 = (const float*)d_in[20];
  float* out = (float*)d_out;  // fp32 output

  char* p = (char*)d_ws;
  auto carve = [&](size_t bytes) {
    char* r = p;
    p += (bytes + 255) & ~(size_t)255;
    return r;
  };
  u16* xh   = (u16*)carve((size_t)B_ROWS * DIM * 2);        // 32MB
  u16* To1  = (u16*)carve((size_t)ORDH * DIM * 2);          // 1MB
  u16* Tr1  = (u16*)carve((size_t)DIM * DIM * 2);           // 2MB
  u16* Ta   = (u16*)carve((size_t)DIM * DIM * 2);           // 2MB
  u16* Te1  = (u16*)carve((size_t)NEXP * DIM * DIM * 2);    // 14MB
  u16* Te2  = (u16*)carve((size_t)NEXP * DIM * DIM * 2);    // 14MB
  float* Y1 = (float*)carve((size_t)B_ROWS * DIM * 4);      // 64MB (cls, fp32)
  u16* Y2   = (u16*)carve((size_t)B_ROWS * ORDH * 2);       // 16MB
  u16* Y3   = (u16*)carve((size_t)B_ROWS * DIM * 2);        // 32MB
  u16* DF   = (u16*)carve((size_t)B_ROWS * DIM * 2);        // 32MB
  float* resv = (float*)carve((size_t)B_ROWS * 4);
  int* size_idx = (int*)carve((size_t)B_ROWS * 4);
  int* perm   = (int*)carve((size_t)B_ROWS * 4);
  int* gcnt   = (int*)carve(256);
  int* off    = (int*)carve(256);
  int* cursor = (int*)carve(256);
  // aliases over dead intervals (stream-ordered; ~209MB total, r6 used 224MB):
  u16* DFp = (u16*)Y1;                                      // Y1 dead after head_cls
  u16* H1p = (u16*)((char*)Y1 + (size_t)B_ROWS * DIM * 2);
  u16* H2p = DF;                                            // DF dead after permute

  dim3 blk(256);
  convert_x_kernel<<<dim3(B_ROWS * DIM / 4 / 256), blk, 0, stream>>>(
      (const float4*)x, (ushort4*)xh);
  transpose_kernel<<<dim3(16, 32, 1), blk, 0, stream>>>(Wo1, To1, DIM, ORDH);
  transpose_kernel<<<dim3(32, 32, 1), blk, 0, stream>>>(Wr1, Tr1, DIM, DIM);
  transpose_kernel<<<dim3(32, 32, 1), blk, 0, stream>>>(Wa, Ta, DIM, DIM);
  transpose_kernel<<<dim3(32, 32, NEXP), blk, 0, stream>>>(We1, Te1, DIM, DIM);
  transpose_kernel<<<dim3(32, 32, NEXP), blk, 0, stream>>>(We2, Te2, DIM, DIM);
  init_kernel<<<dim3(1), dim3(64), 0, stream>>>(gcnt);

  // cls hidden: fp32 vector GEMM (route bit-identical to passing round 6)
  vgemm_kernel<<<dim3(DIM / 64, B_ROWS / 64), blk, 0, stream>>>(
      x, Wc1, DIM, DIM, bc1, Y1, DIM);
  // ord / res / adapter hidden: bf16 MFMA
  mgemm_bt_kernel<<<dim3(ORDH / 128, B_ROWS / 128), blk, 0, stream>>>(
      xh, To1, DIM, bo1, Y2, ORDH);
  mgemm_bt_kernel<<<dim3(DIM / 128, B_ROWS / 128), blk, 0, stream>>>(
      xh, Tr1, DIM, br1, Y3, DIM);
  mgemm_bt_kernel<<<dim3(DIM / 128, B_ROWS / 128), blk, 0, stream>>>(
      xh, Ta, DIM, ba, DF, DIM);

  head_res_kernel<<<dim3(B_ROWS / 4), blk, 0, stream>>>(Y3, Wr2, br2, resv);
  head_ord_kernel<<<dim3(B_ROWS / 4), blk, 0, stream>>>(Y2, Wo2, bo2, out);
  head_cls_kernel<<<dim3(B_ROWS / 4), blk, 0, stream>>>(Y1, Wc2, bc2, resv, out,
                                                        size_idx, gcnt);
  scan_kernel<<<dim3(1), dim3(64), 0, stream>>>(gcnt, off, cursor);
  scatter_kernel<<<dim3(B_ROWS / 256), blk, 0, stream>>>(size_idx, cursor, perm);
  permute_kernel<<<dim3(B_ROWS), blk, 0, stream>>>(DF, perm, DFp);

  mgemm_expert_kernel<<<dim3(DIM / 128, B_ROWS / 128, NEXP), blk, 0, stream>>>(
      DFp, Te1, be1, off, gcnt, H1p);
  mgemm_expert_kernel<<<dim3(DIM / 128, B_ROWS / 128, NEXP), blk, 0, stream>>>(
      H1p, Te2, be2, off, gcnt, H2p);
  head_dl_kernel<<<dim3(B_ROWS / 4), blk, 0, stream>>>(H2p, We3, be3, off, perm, out);
}

// Round 8
// 1711.944 us; speedup vs baseline: 1.5888x; 1.0280x over previous
//
#include <hip/hip_runtime.h>
#include <cstdint>
#include <cstddef>

typedef unsigned short u16;
typedef u16 u16x8 __attribute__((ext_vector_type(8)));
typedef __bf16 bf16x8 __attribute__((ext_vector_type(8)));
typedef float f32x4 __attribute__((ext_vector_type(4)));

#define B_ROWS 16384
#define DIM 1024
#define ORDH 512
#define NEXP 7
#define LDST 72  // LDS row stride in u16 (64 data + 8 pad)

__device__ __forceinline__ u16 f2bf(float f) {
  unsigned u = __builtin_bit_cast(unsigned, f);
  u += 0x7FFFu + ((u >> 16) & 1u);  // RNE
  return (u16)(u >> 16);
}
__device__ __forceinline__ float bf2f(u16 h) {
  return __builtin_bit_cast(float, ((unsigned)h) << 16);
}

__global__ void init_kernel(int* gcnt) {
  if (threadIdx.x < NEXP) gcnt[threadIdx.x] = 0;
}

// x fp32 -> bf16 hi + lo (x ~= hi + lo to ~2^-17 rel)
__global__ __launch_bounds__(256) void convert_x_kernel(
    const float4* __restrict__ x, ushort4* __restrict__ xh,
    ushort4* __restrict__ xl) {
  const int i = blockIdx.x * 256 + threadIdx.x;
  float4 v = x[i];
  ushort4 h, l;
  h.x = f2bf(v.x); l.x = f2bf(v.x - bf2f(h.x));
  h.y = f2bf(v.y); l.y = f2bf(v.y - bf2f(h.y));
  h.z = f2bf(v.z); l.z = f2bf(v.z - bf2f(h.z));
  h.w = f2bf(v.w); l.w = f2bf(v.w - bf2f(h.w));
  xh[i] = h; xl[i] = l;
}

// W [K][N] f32 -> WT [N][K] bf16 (hi, optional lo). grid z = expert batch.
__global__ __launch_bounds__(256) void transpose_kernel(
    const float* __restrict__ W, u16* __restrict__ WTh, u16* __restrict__ WTl,
    int K, int N) {
  __shared__ float tile[32][33];
  const int bk = blockIdx.y * 32, bn = blockIdx.x * 32;
  const int tx = threadIdx.x & 31, ty = threadIdx.x >> 5;  // 32 x 8
  const size_t zoff = (size_t)blockIdx.z * K * N;
#pragma unroll
  for (int r = 0; r < 32; r += 8)
    tile[ty + r][tx] = W[zoff + (size_t)(bk + ty + r) * N + (bn + tx)];
  __syncthreads();
#pragma unroll
  for (int r = 0; r < 32; r += 8) {
    const float v = tile[tx][ty + r];
    const size_t o = zoff + (size_t)(bn + ty + r) * K + (bk + tx);
    const u16 h = f2bf(v);
    WTh[o] = h;
    if (WTl) WTl[o] = f2bf(v - bf2f(h));
  }
}

// ---------------------------------------------------------------------------
// bf16 MFMA GEMM: out = relu(sum_pass A_p * B_p^T + bias); B = WT [N,K] bf16.
// 128x128x64 tile, 4 waves (2x2), 4x4 mfma 16x16x32. Register staging.
// npass=3 + outF used for the cls hidden layer (hi/lo split, fp32 out).
// ---------------------------------------------------------------------------
__global__ __launch_bounds__(256, 2) void mgemm_bt_kernel(
    const u16* __restrict__ A0, const u16* __restrict__ B0,
    const u16* __restrict__ A1, const u16* __restrict__ B1,
    const u16* __restrict__ A2, const u16* __restrict__ B2,
    int npass, int K, const float* __restrict__ bias,
    float* __restrict__ outF, u16* __restrict__ outH, int ldo) {
  __shared__ __attribute__((aligned(16))) u16 As[128 * LDST];
  __shared__ __attribute__((aligned(16))) u16 Bs[128 * LDST];
  const int tid = threadIdx.x;
  const int lane = tid & 63;
  const int w = tid >> 6;
  const int wm = w >> 1, wn = w & 1;
  const int m0 = blockIdx.y * 128;
  const int n0 = blockIdx.x * 128;
  const int sRow = tid >> 3;
  const int sSlot = tid & 7;

  f32x4 acc[4][4] = {};
  for (int pass = 0; pass < npass; ++pass) {
    const u16* Ap = (pass == 0) ? A0 : ((pass == 1) ? A1 : A2);
    const u16* Bp = (pass == 0) ? B0 : ((pass == 1) ? B1 : B2);
    for (int kt = 0; kt < K; kt += 64) {
      int4 av[4], bv[4];
#pragma unroll
      for (int r = 0; r < 4; ++r) {
        const int row = r * 32 + sRow;
        av[r] = *(const int4*)(Ap + (size_t)(m0 + row) * K + kt + sSlot * 8);
        bv[r] = *(const int4*)(Bp + (size_t)(n0 + row) * K + kt + sSlot * 8);
      }
      __syncthreads();
#pragma unroll
      for (int r = 0; r < 4; ++r) {
        const int row = r * 32 + sRow;
        *(int4*)&As[row * LDST + sSlot * 8] = av[r];
        *(int4*)&Bs[row * LDST + sSlot * 8] = bv[r];
      }
      __syncthreads();
#pragma unroll
      for (int s = 0; s < 2; ++s) {
        bf16x8 af[4], bfr[4];
        const int cA = s * 4 + (lane >> 4);
#pragma unroll
        for (int t = 0; t < 4; ++t) {
          const int rowA = wm * 64 + t * 16 + (lane & 15);
          af[t] = __builtin_bit_cast(bf16x8, *(const u16x8*)&As[rowA * LDST + cA * 8]);
          const int rowB = wn * 64 + t * 16 + (lane & 15);
          bfr[t] = __builtin_bit_cast(bf16x8, *(const u16x8*)&Bs[rowB * LDST + cA * 8]);
        }
#pragma unroll
        for (int mt = 0; mt < 4; ++mt)
#pragma unroll
          for (int nt = 0; nt < 4; ++nt)
            acc[mt][nt] = __builtin_amdgcn_mfma_f32_16x16x32_bf16(
                af[mt], bfr[nt], acc[mt][nt], 0, 0, 0);
      }
    }
  }
  const int q = lane >> 4, cl = lane & 15;
#pragma unroll
  for (int nt = 0; nt < 4; ++nt) {
    const int col = n0 + wn * 64 + nt * 16 + cl;
    const float bv = bias[col];
#pragma unroll
    for (int mt = 0; mt < 4; ++mt) {
#pragma unroll
      for (int i = 0; i < 4; ++i) {
        const int row = m0 + wm * 64 + mt * 16 + q * 4 + i;
        float v = acc[mt][nt][i] + bv;
        v = v > 0.f ? v : 0.f;
        if (outF) outF[(size_t)row * ldo + col] = v;
        else      outH[(size_t)row * ldo + col] = f2bf(v);
      }
    }
  }
}

// expert-segmented MFMA variant: rows [off[e]+t0, off[e]+cnt[e])
__global__ __launch_bounds__(256, 2) void mgemm_expert_kernel(
    const u16* __restrict__ Abuf, const u16* __restrict__ Wall,
    const float* __restrict__ biasAll, const int* __restrict__ off,
    const int* __restrict__ cnt, u16* __restrict__ outH) {
  __shared__ __attribute__((aligned(16))) u16 As[128 * LDST];
  __shared__ __attribute__((aligned(16))) u16 Bs[128 * LDST];
  const int e = blockIdx.z;
  const int myCnt = cnt[e];
  const int t0 = blockIdx.y * 128;
  if (t0 >= myCnt) return;  // uniform per block
  const int base = off[e];
  const int m0 = base + t0;
  const int mEnd = base + myCnt;
  const u16* Bp = Wall + (size_t)e * DIM * DIM;
  const float* bias = biasAll + (size_t)e * DIM;

  const int tid = threadIdx.x;
  const int lane = tid & 63;
  const int w = tid >> 6;
  const int wm = w >> 1, wn = w & 1;
  const int n0 = blockIdx.x * 128;
  const int sRow = tid >> 3;
  const int sSlot = tid & 7;

  f32x4 acc[4][4] = {};
  for (int kt = 0; kt < DIM; kt += 64) {
    int4 av[4], bv[4];
#pragma unroll
    for (int r = 0; r < 4; ++r) {
      int ar = m0 + r * 32 + sRow;
      if (ar > B_ROWS - 1) ar = B_ROWS - 1;  // clamp; masked at store
      av[r] = *(const int4*)(Abuf + (size_t)ar * DIM + kt + sSlot * 8);
      bv[r] = *(const int4*)(Bp + (size_t)(n0 + r * 32 + sRow) * DIM + kt + sSlot * 8);
    }
    __syncthreads();
#pragma unroll
    for (int r = 0; r < 4; ++r) {
      const int row = r * 32 + sRow;
      *(int4*)&As[row * LDST + sSlot * 8] = av[r];
      *(int4*)&Bs[row * LDST + sSlot * 8] = bv[r];
    }
    __syncthreads();
#pragma unroll
    for (int s = 0; s < 2; ++s) {
      bf16x8 af[4], bfr[4];
      const int cA = s * 4 + (lane >> 4);
#pragma unroll
      for (int t = 0; t < 4; ++t) {
        const int rowA = wm * 64 + t * 16 + (lane & 15);
        af[t] = __builtin_bit_cast(bf16x8, *(const u16x8*)&As[rowA * LDST + cA * 8]);
        const int rowB = wn * 64 + t * 16 + (lane & 15);
        bfr[t] = __builtin_bit_cast(bf16x8, *(const u16x8*)&Bs[rowB * LDST + cA * 8]);
      }
#pragma unroll
      for (int mt = 0; mt < 4; ++mt)
#pragma unroll
        for (int nt = 0; nt < 4; ++nt)
          acc[mt][nt] = __builtin_amdgcn_mfma_f32_16x16x32_bf16(
              af[mt], bfr[nt], acc[mt][nt], 0, 0, 0);
    }
  }
  const int q = lane >> 4, cl = lane & 15;
#pragma unroll
  for (int nt = 0; nt < 4; ++nt) {
    const int col = n0 + wn * 64 + nt * 16 + cl;
    const float bv = bias[col];
#pragma unroll
    for (int mt = 0; mt < 4; ++mt) {
#pragma unroll
      for (int i = 0; i < 4; ++i) {
        const int row = m0 + wm * 64 + mt * 16 + q * 4 + i;
        if (row < mEnd) {
          float v = acc[mt][nt][i] + bv;
          v = v > 0.f ? v : 0.f;
          outH[(size_t)row * DIM + col] = f2bf(v);
        }
      }
    }
  }
}

// ---------------------------------------------------------------------------
// heads: one wave per row. OUTPUT fp32.
// ---------------------------------------------------------------------------
__global__ __launch_bounds__(256) void head_res_kernel(
    const u16* __restrict__ Y3, const float* __restrict__ Wr2,
    const float* __restrict__ br2, float* __restrict__ resv) {
  const int lane = threadIdx.x & 63;
  const int r = blockIdx.x * 4 + (threadIdx.x >> 6);
  float s = 0.f;
  for (int it = 0; it < 16; ++it) {
    const int k = it * 64 + lane;
    s += bf2f(Y3[(size_t)r * DIM + k]) * Wr2[k];
  }
  for (int o = 32; o > 0; o >>= 1) s += __shfl_down(s, o);
  if (lane == 0) resv[r] = 0.35f * tanhf(s + br2[0]);
}

__global__ __launch_bounds__(256) void head_ord_kernel(
    const u16* __restrict__ Y2, const float* __restrict__ Wo2,
    const float* __restrict__ bo2, float* __restrict__ out) {
  const int lane = threadIdx.x & 63;
  const int r = blockIdx.x * 4 + (threadIdx.x >> 6);
  float s[6] = {0, 0, 0, 0, 0, 0};
  for (int it = 0; it < 8; ++it) {
    const int k = it * 64 + lane;
    const float v = bf2f(Y2[(size_t)r * ORDH + k]);
    const float* wr = Wo2 + k * 6;
#pragma unroll
    for (int n = 0; n < 6; ++n) s[n] += v * wr[n];
  }
#pragma unroll
  for (int n = 0; n < 6; ++n) {
    float xv = s[n];
    for (int o = 32; o > 0; o >>= 1) xv += __shfl_down(xv, o);
    s[n] = xv;
  }
  if (lane == 0) {
#pragma unroll
    for (int n = 0; n < 6; ++n) out[(size_t)r * 24 + 7 + n] = s[n] + bo2[n];
  }
}

__global__ __launch_bounds__(256) void head_cls_kernel(
    const float* __restrict__ Y1, const float* __restrict__ Wc2,
    const float* __restrict__ bc2, const float* __restrict__ resv,
    float* __restrict__ out, int* __restrict__ size_idx, int* __restrict__ gcnt) {
  __shared__ int lcnt[NEXP];
  const int tid = threadIdx.x;
  if (tid < NEXP) lcnt[tid] = 0;
  __syncthreads();
  const int lane = tid & 63;
  const int r = blockIdx.x * 4 + (tid >> 6);
  float s[7] = {0, 0, 0, 0, 0, 0, 0};
  for (int it = 0; it < 16; ++it) {
    const int k = it * 64 + lane;
    const float v = Y1[(size_t)r * DIM + k];
    const float* wr = Wc2 + k * 7;
#pragma unroll
    for (int n = 0; n < 7; ++n) s[n] += v * wr[n];
  }
#pragma unroll
  for (int n = 0; n < 7; ++n) {
    float xv = s[n];
    for (int o = 32; o > 0; o >>= 1) xv += __shfl_down(xv, o);
    s[n] = xv;
  }
  if (lane == 0) {
    float lg[7], p[7];
    float m = -1e30f;
    int ai = 0;
#pragma unroll
    for (int n = 0; n < 7; ++n) {
      lg[n] = s[n] + bc2[n];
      if (lg[n] > m) { m = lg[n]; ai = n; }  // first max == np.argmax
    }
    float es = 0.f;
#pragma unroll
    for (int n = 0; n < 7; ++n) { p[n] = expf(lg[n] - m); es += p[n]; }
    const float inv = 1.f / es;
    float expect = 0.f;
#pragma unroll
    for (int n = 0; n < 7; ++n) { p[n] *= inv; expect += p[n] * (n * (1.f / 6.f)); }
    float reg = expect + resv[r];
    reg = fminf(fmaxf(reg, 0.f), 1.f);
    float* orow = out + (size_t)r * 24;
#pragma unroll
    for (int n = 0; n < 7; ++n) orow[n] = lg[n];
    orow[13] = reg;
#pragma unroll
    for (int n = 0; n < 7; ++n) orow[14 + n] = p[n];
    size_idx[r] = ai;
    atomicAdd(&lcnt[ai], 1);
  }
  __syncthreads();
  if (tid < NEXP && lcnt[tid] > 0) atomicAdd(&gcnt[tid], lcnt[tid]);
}

__global__ void scan_kernel(const int* __restrict__ gcnt, int* __restrict__ off,
                            int* __restrict__ cursor) {
  if (threadIdx.x == 0) {
    int a = 0;
    for (int e = 0; e < NEXP; ++e) { off[e] = a; cursor[e] = a; a += gcnt[e]; }
    off[NEXP] = a;
  }
}

__global__ __launch_bounds__(256) void scatter_kernel(
    const int* __restrict__ size_idx, int* __restrict__ cursor,
    int* __restrict__ perm) {
  __shared__ int lcnt[NEXP];
  __shared__ int lbase[NEXP];
  const int tid = threadIdx.x;
  if (tid < NEXP) lcnt[tid] = 0;
  __syncthreads();
  const int r = blockIdx.x * 256 + tid;
  const int e = size_idx[r];
  const int lp = atomicAdd(&lcnt[e], 1);
  __syncthreads();
  if (tid < NEXP && lcnt[tid] > 0) lbase[tid] = atomicAdd(&cursor[tid], lcnt[tid]);
  __syncthreads();
  perm[lbase[e] + lp] = r;
}

__global__ __launch_bounds__(256) void permute_kernel(
    const u16* __restrict__ DF, const int* __restrict__ perm,
    u16* __restrict__ DFp) {
  const int i = blockIdx.x;
  const int src = perm[i];
  const uint2* s = (const uint2*)(DF + (size_t)src * DIM);
  uint2* d = (uint2*)(DFp + (size_t)i * DIM);
  d[threadIdx.x] = s[threadIdx.x];
}

__global__ __launch_bounds__(256) void head_dl_kernel(
    const u16* __restrict__ H2p, const float* __restrict__ We3,
    const float* __restrict__ be3, const int* __restrict__ off,
    const int* __restrict__ perm, float* __restrict__ out) {
  const int lane = threadIdx.x & 63;
  const int i = blockIdx.x * 4 + (threadIdx.x >> 6);
  int e = 0;
#pragma unroll
  for (int t = 1; t < NEXP; ++t)
    if (i >= off[t]) e = t;
  const float* W = We3 + (size_t)e * DIM * 3;
  float s0 = 0.f, s1 = 0.f, s2 = 0.f;
  for (int it = 0; it < 16; ++it) {
    const int k = it * 64 + lane;
    const float v = bf2f(H2p[(size_t)i * DIM + k]);
    s0 += v * W[k * 3 + 0];
    s1 += v * W[k * 3 + 1];
    s2 += v * W[k * 3 + 2];
  }
  for (int o = 32; o > 0; o >>= 1) {
    s0 += __shfl_down(s0, o);
    s1 += __shfl_down(s1, o);
    s2 += __shfl_down(s2, o);
  }
  if (lane == 0) {
    const int r = perm[i];
    float* orow = out + (size_t)r * 24;
    orow[21] = s0 + be3[e * 3 + 0];
    orow[22] = s1 + be3[e * 3 + 1];
    orow[23] = s2 + be3[e * 3 + 2];
  }
}

// ---------------------------------------------------------------------------
extern "C" void kernel_launch(void* const* d_in, const int* in_sizes, int n_in,
                              void* d_out, int out_size, void* d_ws, size_t ws_size,
                              hipStream_t stream) {
  (void)in_sizes; (void)n_in; (void)out_size; (void)ws_size;
  const float* x   = (const float*)d_in[0];
  const float* Wc1 = (const float*)d_in[1];
  const float* bc1 = (const float*)d_in[2];
  const float* Wc2 = (const float*)d_in[3];
  const float* bc2 = (const float*)d_in[4];
  const float* Wo1 = (const float*)d_in[5];
  const float* bo1 = (const float*)d_in[6];
  const float* Wo2 = (const float*)d_in[7];
  const float* bo2 = (const float*)d_in[8];
  const float* Wr1 = (const float*)d_in[9];
  const float* br1 = (const float*)d_in[10];
  const float* Wr2 = (const float*)d_in[11];
  const float* br2 = (const float*)d_in[12];
  const float* Wa  = (const float*)d_in[13];
  const float* ba  = (const float*)d_in[14];
  const float* We1 = (const float*)d_in[15];
  const float* be1 = (const float*)d_in[16];
  const float* We2 = (const float*)d_in[17];
  const float* be2 = (const float*)d_in[18];
  const float* We3 = (const float*)d_in[19];
  const float* be3 = (const float*)d_in[20];
  float* out = (float*)d_out;  // fp32 output

  char* p = (char*)d_ws;
  auto carve = [&](size_t bytes) {
    char* r = p;
    p += (bytes + 255) & ~(size_t)255;
    return r;
  };
  // total ~197 MB (ws >= 236 MB confirmed in rounds 4/5)
  u16* xh   = (u16*)carve((size_t)B_ROWS * DIM * 2);      // 32MB
  u16* xl   = (u16*)carve((size_t)B_ROWS * DIM * 2);      // 32MB (dead after cls)
  u16* Tc1h = (u16*)carve((size_t)DIM * DIM * 2);         // 2MB
  u16* Tc1l = (u16*)carve((size_t)DIM * DIM * 2);         // 2MB
  u16* To1  = (u16*)carve((size_t)ORDH * DIM * 2);        // 1MB
  u16* Tr1  = (u16*)carve((size_t)DIM * DIM * 2);         // 2MB
  u16* Ta   = (u16*)carve((size_t)DIM * DIM * 2);         // 2MB
  u16* Te1  = (u16*)carve((size_t)NEXP * DIM * DIM * 2);  // 14MB
  u16* Te2  = (u16*)carve((size_t)NEXP * DIM * DIM * 2);  // 14MB
  u16* Y3   = (u16*)carve((size_t)B_ROWS * DIM * 2);      // 32MB (res hidden)
  u16* Y2   = (u16*)carve((size_t)B_ROWS * ORDH * 2);     // 16MB (ord hidden)
  carve((size_t)16 << 20);                                // 16MB pad (tail of Y1)
  u16* DF   = (u16*)carve((size_t)B_ROWS * DIM * 2);      // 32MB
  float* resv = (float*)carve((size_t)B_ROWS * 4);
  int* size_idx = (int*)carve((size_t)B_ROWS * 4);
  int* perm   = (int*)carve((size_t)B_ROWS * 4);
  int* gcnt   = (int*)carve(256);
  int* off    = (int*)carve(256);
  int* cursor = (int*)carve(256);
  // aliases over dead intervals (stream-ordered):
  float* Y1 = (float*)Y3;   // 64MB = Y3(32)+Y2(16)+pad(16); Y3/Y2 dead after their heads
  u16* DFp = xl;            // xl dead after cls 3-pass GEMM
  u16* H1p = Y3;            // Y1 dead after head_cls
  u16* H2p = DF;            // DF dead after permute

  dim3 blk(256);
  convert_x_kernel<<<dim3(B_ROWS * DIM / 4 / 256), blk, 0, stream>>>(
      (const float4*)x, (ushort4*)xh, (ushort4*)xl);
  transpose_kernel<<<dim3(32, 32, 1), blk, 0, stream>>>(Wc1, Tc1h, Tc1l, DIM, DIM);
  transpose_kernel<<<dim3(16, 32, 1), blk, 0, stream>>>(Wo1, To1, (u16*)nullptr, DIM, ORDH);
  transpose_kernel<<<dim3(32, 32, 1), blk, 0, stream>>>(Wr1, Tr1, (u16*)nullptr, DIM, DIM);
  transpose_kernel<<<dim3(32, 32, 1), blk, 0, stream>>>(Wa, Ta, (u16*)nullptr, DIM, DIM);
  transpose_kernel<<<dim3(32, 32, NEXP), blk, 0, stream>>>(We1, Te1, (u16*)nullptr, DIM, DIM);
  transpose_kernel<<<dim3(32, 32, NEXP), blk, 0, stream>>>(We2, Te2, (u16*)nullptr, DIM, DIM);
  init_kernel<<<dim3(1), dim3(64), 0, stream>>>(gcnt);

  // ord / res / adapter hidden first (their outputs die before Y1 is written)
  mgemm_bt_kernel<<<dim3(ORDH / 128, B_ROWS / 128), blk, 0, stream>>>(
      xh, To1, nullptr, nullptr, nullptr, nullptr, 1, DIM, bo1,
      (float*)nullptr, Y2, ORDH);
  mgemm_bt_kernel<<<dim3(DIM / 128, B_ROWS / 128), blk, 0, stream>>>(
      xh, Tr1, nullptr, nullptr, nullptr, nullptr, 1, DIM, br1,
      (float*)nullptr, Y3, DIM);
  mgemm_bt_kernel<<<dim3(DIM / 128, B_ROWS / 128), blk, 0, stream>>>(
      xh, Ta, nullptr, nullptr, nullptr, nullptr, 1, DIM, ba,
      (float*)nullptr, DF, DIM);
  head_res_kernel<<<dim3(B_ROWS / 4), blk, 0, stream>>>(Y3, Wr2, br2, resv);
  head_ord_kernel<<<dim3(B_ROWS / 4), blk, 0, stream>>>(Y2, Wo2, bo2, out);

  // cls hidden: 3-pass hi/lo MFMA -> fp32 Y1 (route-faithful, ~5e-6 logit err)
  mgemm_bt_kernel<<<dim3(DIM / 128, B_ROWS / 128), blk, 0, stream>>>(
      xh, Tc1h, xh, Tc1l, xl, Tc1h, 3, DIM, bc1, Y1, (u16*)nullptr, DIM);
  head_cls_kernel<<<dim3(B_ROWS / 4), blk, 0, stream>>>(Y1, Wc2, bc2, resv, out,
                                                        size_idx, gcnt);
  scan_kernel<<<dim3(1), dim3(64), 0, stream>>>(gcnt, off, cursor);
  scatter_kernel<<<dim3(B_ROWS / 256), blk, 0, stream>>>(size_idx, cursor, perm);
  permute_kernel<<<dim3(B_ROWS), blk, 0, stream>>>(DF, perm, DFp);

  mgemm_expert_kernel<<<dim3(DIM / 128, B_ROWS / 128, NEXP), blk, 0, stream>>>(
      DFp, Te1, be1, off, gcnt, H1p);
  mgemm_expert_kernel<<<dim3(DIM / 128, B_ROWS / 128, NEXP), blk, 0, stream>>>(
      H1p, Te2, be2, off, gcnt, H2p);
  head_dl_kernel<<<dim3(B_ROWS / 4), blk, 0, stream>>>(H2p, We3, be3, off, perm, out);
}